// Round 1
// baseline (594.046 us; speedup 1.0000x reference)
//
#include <hip/hip_runtime.h>
#include <cstdint>
#include <cstddef>

#define B_SZ 8
#define N1 4096
#define N2 256
#define LTOT 4352          // N1 + N2
#define DIMD 1024
#define HEADS 16
#define DH 64
#define MKV (B_SZ * LTOT)  // 34816

typedef _Float16 f16;
typedef f16 f16x4_t __attribute__((ext_vector_type(4)));
typedef f16 f16x8_t __attribute__((ext_vector_type(8)));
typedef float f32x4_t __attribute__((ext_vector_type(4)));

// async global -> LDS, 16B per lane. LDS dest is wave-uniform base + lane*16.
__device__ __forceinline__ void g2l16(const void* g, void* l) {
  __builtin_amdgcn_global_load_lds(
      (__attribute__((address_space(1))) void*)g,
      (__attribute__((address_space(3))) void*)l, 16, 0, 0);
}

// ---------------------------------------------------------------------------
// Kernel 1: layernorm (+ latent modulation), f32 -> f16, into concat kv_in
// rows [b*4352 + 0..4095] = ln1(x), rows [b*4352 + 4096..4351] = mod(ln2(lat))
// ---------------------------------------------------------------------------
__global__ __launch_bounds__(256) void ln_mod_kernel(
    const float* __restrict__ x, const float* __restrict__ lat,
    const float* __restrict__ shift, const float* __restrict__ scale,
    const float* __restrict__ ln1w, const float* __restrict__ ln1b,
    const float* __restrict__ ln2w, const float* __restrict__ ln2b,
    f16* __restrict__ kv_in) {
  const int row = blockIdx.x;
  const int b = row / LTOT;
  const int n = row - b * LTOT;
  const int tid = threadIdx.x;
  const bool is_lat = (n >= N1);
  const float* src = is_lat ? (lat + (size_t)(b * N2 + (n - N1)) * DIMD)
                            : (x + (size_t)(b * N1 + n) * DIMD);
  float4 v = ((const float4*)src)[tid];
  float s = v.x + v.y + v.z + v.w;
  float s2 = v.x * v.x + v.y * v.y + v.z * v.z + v.w * v.w;
#pragma unroll
  for (int m = 1; m <= 32; m <<= 1) {
    s += __shfl_xor(s, m, 64);
    s2 += __shfl_xor(s2, m, 64);
  }
  __shared__ float red[8];
  const int wave = tid >> 6;
  if ((tid & 63) == 0) { red[wave * 2] = s; red[wave * 2 + 1] = s2; }
  __syncthreads();
  s = red[0] + red[2] + red[4] + red[6];
  s2 = red[1] + red[3] + red[5] + red[7];
  const float mean = s * (1.0f / DIMD);
  const float var = fmaxf(s2 * (1.0f / DIMD) - mean * mean, 0.0f);
  const float rstd = rsqrtf(var + 1e-5f);
  const float4 w4 = ((const float4*)(is_lat ? ln2w : ln1w))[tid];
  const float4 b4 = ((const float4*)(is_lat ? ln2b : ln1b))[tid];
  float y0 = (v.x - mean) * rstd * w4.x + b4.x;
  float y1 = (v.y - mean) * rstd * w4.y + b4.y;
  float y2 = (v.z - mean) * rstd * w4.z + b4.z;
  float y3 = (v.w - mean) * rstd * w4.w + b4.w;
  if (is_lat) {
    float4 sc = ((const float4*)(scale + (size_t)b * DIMD))[tid];
    float4 sh = ((const float4*)(shift + (size_t)b * DIMD))[tid];
    y0 = y0 * (1.0f + sc.x) + sh.x;
    y1 = y1 * (1.0f + sc.y) + sh.y;
    y2 = y2 * (1.0f + sc.z) + sh.z;
    y3 = y3 * (1.0f + sc.w) + sh.w;
  }
  f16x4_t o = {(f16)y0, (f16)y1, (f16)y2, (f16)y3};
  *(f16x4_t*)(kv_in + (size_t)row * DIMD + tid * 4) = o;
}

// ---------------------------------------------------------------------------
// Kernel 2: f32 -> f16 cast (weights)
// ---------------------------------------------------------------------------
__global__ __launch_bounds__(256) void cast_kernel(const float* __restrict__ in,
                                                   f16* __restrict__ out, int n4) {
  const int i = blockIdx.x * 256 + threadIdx.x;
  if (i < n4) {
    float4 v = ((const float4*)in)[i];
    f16x4_t o = {(f16)v.x, (f16)v.y, (f16)v.z, (f16)v.w};
    ((f16x4_t*)out)[i] = o;
  }
}

// ---------------------------------------------------------------------------
// Kernel 3: 128x128-tile GEMM, C = A (MxK rowmajor f16) * BT (NxK rowmajor f16)
// m97 structure: BK=32, global_load_lds 16B staging, 16x16x32 f16 MFMA.
// MODE 0: kv GEMM -> scatter to k_buf (b,h,n,d) and v_buf transposed (b,h,d,n)
// MODE 1: q GEMM (A rows = latent rows inside kv_in) -> q_buf (b,h,n,d)
// MODE 2: out GEMM -> f32 d_out
// ---------------------------------------------------------------------------
template <int MODE>
__global__ __launch_bounds__(256) void gemm128(
    const f16* __restrict__ A0, const f16* __restrict__ BT,
    void* __restrict__ out0, void* __restrict__ out1) {
  const int mt = blockIdx.x, nt = blockIdx.y;
  const f16* Abase;
  if (MODE == 1) {
    const int bb = mt >> 1;
    Abase = A0 + ((size_t)(bb * LTOT + N1 + (mt & 1) * 128)) * DIMD;
  } else {
    Abase = A0 + (size_t)mt * 128 * DIMD;
  }
  const f16* Bbase = BT + (size_t)nt * 128 * DIMD;
  __shared__ alignas(16) f16 As[128 * 32];
  __shared__ alignas(16) f16 Bs[128 * 32];
  const int tid = threadIdx.x;
  const int wave = tid >> 6, lane = tid & 63;
  const int wm = (wave & 1) * 64, wn = (wave >> 1) * 64;
  const int lrow = lane >> 2, lcol = (lane & 3) * 8;
  const int r16 = lane & 15, g8 = (lane >> 4) * 8, q4 = (lane >> 4) * 4;
  f32x4_t acc[4][4] = {};
  for (int k0 = 0; k0 < DIMD; k0 += 32) {
    __syncthreads();
    g2l16(Abase + (size_t)(wave * 16 + lrow) * DIMD + k0 + lcol, &As[(wave * 16) * 32]);
    g2l16(Abase + (size_t)(64 + wave * 16 + lrow) * DIMD + k0 + lcol, &As[(64 + wave * 16) * 32]);
    g2l16(Bbase + (size_t)(wave * 16 + lrow) * DIMD + k0 + lcol, &Bs[(wave * 16) * 32]);
    g2l16(Bbase + (size_t)(64 + wave * 16 + lrow) * DIMD + k0 + lcol, &Bs[(64 + wave * 16) * 32]);
    __syncthreads();
    f16x8_t a[4], bf[4];
#pragma unroll
    for (int i = 0; i < 4; i++)
      a[i] = *(const f16x8_t*)&As[(wm + i * 16 + r16) * 32 + g8];
#pragma unroll
    for (int j = 0; j < 4; j++)
      bf[j] = *(const f16x8_t*)&Bs[(wn + j * 16 + r16) * 32 + g8];
#pragma unroll
    for (int i = 0; i < 4; i++)
#pragma unroll
      for (int j = 0; j < 4; j++)
        acc[i][j] = __builtin_amdgcn_mfma_f32_16x16x32_f16(a[i], bf[j], acc[i][j], 0, 0, 0);
  }

  if constexpr (MODE == 0) {
    const int m0 = mt * 128;
    const int b = m0 / LTOT;
    const int n0 = m0 - b * LTOT;
    const int e0 = nt * 128;
    if (e0 < 1024) {  // k half: layout ((b*16+h)*4352 + n)*64 + d
      f16* kbuf = (f16*)out0;
#pragma unroll
      for (int i = 0; i < 4; i++) {
        const int n_base = n0 + wm + i * 16 + q4;
#pragma unroll
        for (int j = 0; j < 4; j++) {
          const int e = e0 + wn + j * 16 + r16;
          const int h = e >> 6, d = e & 63;
          const size_t base = ((size_t)(b * HEADS + h) * LTOT);
#pragma unroll
          for (int r = 0; r < 4; r++)
            kbuf[(base + n_base + r) * DH + d] = (f16)acc[i][j][r];
        }
      }
    } else {  // v half, transposed: ((b*16+h)*64 + d)*4352 + n
      f16* vbuf = (f16*)out1;
      const int e0v = e0 - 1024;
#pragma unroll
      for (int i = 0; i < 4; i++) {
        const int n_base = n0 + wm + i * 16 + q4;
#pragma unroll
        for (int j = 0; j < 4; j++) {
          const int e = e0v + wn + j * 16 + r16;
          const int h = e >> 6, d = e & 63;
          f16x4_t pk = {(f16)acc[i][j][0], (f16)acc[i][j][1],
                        (f16)acc[i][j][2], (f16)acc[i][j][3]};
          *(f16x4_t*)&vbuf[((size_t)(b * HEADS + h) * DH + d) * LTOT + n_base] = pk;
        }
      }
    }
  } else if constexpr (MODE == 1) {  // q: ((b*16+h)*256 + n)*64 + d
    f16* qbuf = (f16*)out0;
    const int b = mt >> 1;
#pragma unroll
    for (int i = 0; i < 4; i++) {
      const int n_base = (mt & 1) * 128 + wm + i * 16 + q4;
#pragma unroll
      for (int j = 0; j < 4; j++) {
        const int e = nt * 128 + wn + j * 16 + r16;
        const int h = e >> 6, d = e & 63;
#pragma unroll
        for (int r = 0; r < 4; r++)
          qbuf[((size_t)(b * HEADS + h) * N2 + n_base + r) * DH + d] = (f16)acc[i][j][r];
      }
    }
  } else {  // final output, f32
    float* outp = (float*)out0;
    const int m0 = mt * 128;
#pragma unroll
    for (int i = 0; i < 4; i++) {
#pragma unroll
      for (int j = 0; j < 4; j++) {
        const int col = nt * 128 + wn + j * 16 + r16;
#pragma unroll
        for (int r = 0; r < 4; r++)
          outp[(size_t)(m0 + wm + i * 16 + q4 + r) * DIMD + col] = acc[i][j][r];
      }
    }
  }
}

// ---------------------------------------------------------------------------
// Kernel 4: flash attention, transposed compute.
//   S^T = K * Q^T    (A = K tile rowmajor, B^T = Q rowmajor)
//   O^T = Vt * P^T   (A = Vt tile rowmajor, B^T = P rowmajor)
// Each wave owns 32 q-columns; softmax stats wave-local (shfl over hi lanes).
// LDS aliasing: Rh = [K tile 16KB | Q tile 16KB(+)], P (34816B) overlays Rh.
// ---------------------------------------------------------------------------
__global__ __launch_bounds__(256, 1) void attn_kernel(
    const f16* __restrict__ qbuf, const f16* __restrict__ kbuf,
    const f16* __restrict__ vbuf, f16* __restrict__ attn_out) {
  const int bh = blockIdx.x >> 1;
  const int qt = blockIdx.x & 1;
  const int b = bh >> 4, h = bh & 15;
  const f16* qg = qbuf + ((size_t)bh * N2 + qt * 128) * DH;
  const f16* kg = kbuf + (size_t)bh * LTOT * DH;
  const f16* vg = vbuf + (size_t)bh * DH * LTOT;

  __shared__ alignas(16) f16 Rh[17408];       // 34816 B (K|Q, later P)
  __shared__ alignas(16) f16 Vs[4][64 * 32];  // 16384 B, Vt in 4 key-chunks

  const int tid = threadIdx.x, wave = tid >> 6, lane = tid & 63;
  const int lrow = lane >> 2, lcol = (lane & 3) * 8;
  const int r16 = lane & 15, g8 = (lane >> 4) * 8, q4 = (lane >> 4) * 4;
  f16* Ps = &Rh[wave * 4352];  // 32 rows x 136 halves, per-wave private

  // stage Q once into Rh[8192..), then hold fragments in registers
#pragma unroll
  for (int s = 0; s < 2; s++)
#pragma unroll
    for (int half = 0; half < 2; half++) {
      const int r0 = half * 64 + wave * 16;
      g2l16(qg + (size_t)(r0 + lrow) * DH + s * 32 + lcol,
            &Rh[8192 + s * 4096 + r0 * 32]);
    }
  __syncthreads();
  f16x8_t bQ[2][2];
#pragma unroll
  for (int s = 0; s < 2; s++)
#pragma unroll
    for (int j = 0; j < 2; j++)
      bQ[s][j] = *(const f16x8_t*)&Rh[8192 + s * 4096 + (wave * 32 + j * 16 + r16) * 32 + g8];

  f32x4_t oacc[4][2] = {};
  float mrow[2] = {-1e30f, -1e30f};
  float lsum[2] = {0.0f, 0.0f};
  const float SCL = 0.125f * 1.44269504089f;  // fold attn_scale^2 and log2(e)

  for (int kt = 0; kt < LTOT / 128; kt++) {
    __syncthreads();  // prior-iteration LDS reads drained
    // stage K tile (2 d-halves) into Rh[0..8192)
#pragma unroll
    for (int s = 0; s < 2; s++)
#pragma unroll
      for (int half = 0; half < 2; half++) {
        const int r0 = half * 64 + wave * 16;
        g2l16(kg + (size_t)(kt * 128 + r0 + lrow) * DH + s * 32 + lcol,
              &Rh[s * 4096 + r0 * 32]);
      }
    // stage Vt key-chunk (wave w handles chunk w)
#pragma unroll
    for (int dg = 0; dg < 4; dg++) {
      const int d0 = dg * 16;
      g2l16(vg + (size_t)(d0 + lrow) * LTOT + kt * 128 + wave * 32 + lcol,
            &Vs[wave][d0 * 32]);
    }
    __syncthreads();
    // S^T = K * Q^T
    f32x4_t sacc[8][2] = {};
#pragma unroll
    for (int s = 0; s < 2; s++) {
      f16x8_t aK[8];
#pragma unroll
      for (int i = 0; i < 8; i++)
        aK[i] = *(const f16x8_t*)&Rh[s * 4096 + (i * 16 + r16) * 32 + g8];
#pragma unroll
      for (int i = 0; i < 8; i++)
#pragma unroll
        for (int j = 0; j < 2; j++)
          sacc[i][j] = __builtin_amdgcn_mfma_f32_16x16x32_f16(aK[i], bQ[s][j], sacc[i][j], 0, 0, 0);
    }
    __syncthreads();  // all waves done reading K before P overlays Rh
    // online softmax, base-2 domain; per-lane qcol = j*16 + (lane&15)
#pragma unroll
    for (int j = 0; j < 2; j++) {
      float vmax = -1e30f;
#pragma unroll
      for (int i = 0; i < 8; i++)
#pragma unroll
        for (int r = 0; r < 4; r++) vmax = fmaxf(vmax, sacc[i][j][r]);
      vmax = fmaxf(vmax, __shfl_xor(vmax, 16, 64));
      vmax = fmaxf(vmax, __shfl_xor(vmax, 32, 64));
      const float m_new = fmaxf(mrow[j], SCL * vmax);
      const float alpha = exp2f(mrow[j] - m_new);
      float psum = 0.0f;
#pragma unroll
      for (int i = 0; i < 8; i++) {
        f16x4_t pk;
#pragma unroll
        for (int r = 0; r < 4; r++) {
          const float p = exp2f(SCL * sacc[i][j][r] - m_new);
          psum += p;
          pk[r] = (f16)p;
        }
        *(f16x4_t*)&Ps[(j * 16 + r16) * 136 + i * 16 + q4] = pk;  // key consec in r
      }
      psum += __shfl_xor(psum, 16, 64);
      psum += __shfl_xor(psum, 32, 64);
      lsum[j] = lsum[j] * alpha + psum;
      mrow[j] = m_new;
#pragma unroll
      for (int id = 0; id < 4; id++) oacc[id][j] *= alpha;
    }
    // O^T += Vt * P^T  (per-wave private P, DS ops in-order -> no barrier)
#pragma unroll
    for (int s2 = 0; s2 < 4; s2++) {
      f16x8_t aV[4];
#pragma unroll
      for (int id = 0; id < 4; id++)
        aV[id] = *(const f16x8_t*)&Vs[s2][(id * 16 + r16) * 32 + g8];
      f16x8_t bP[2];
#pragma unroll
      for (int j = 0; j < 2; j++)
        bP[j] = *(const f16x8_t*)&Ps[(j * 16 + r16) * 136 + s2 * 32 + g8];
#pragma unroll
      for (int id = 0; id < 4; id++)
#pragma unroll
        for (int j = 0; j < 2; j++)
          oacc[id][j] = __builtin_amdgcn_mfma_f32_16x16x32_f16(aV[id], bP[j], oacc[id][j], 0, 0, 0);
    }
  }
  // epilogue: attn_out[(b*256+qrow)*1024 + h*64 + d], f16 rowmajor for out-GEMM
#pragma unroll
  for (int j = 0; j < 2; j++) {
    const float inv = 1.0f / lsum[j];
    const int qrow = qt * 128 + wave * 32 + j * 16 + r16;
    const size_t rowbase = ((size_t)(b * N2 + qrow)) * DIMD + h * DH;
#pragma unroll
    for (int id = 0; id < 4; id++) {
      f16x4_t pk;
#pragma unroll
      for (int r = 0; r < 4; r++) pk[r] = (f16)(oacc[id][j][r] * inv);
      *(f16x4_t*)&attn_out[rowbase + id * 16 + q4] = pk;
    }
  }
}

// ---------------------------------------------------------------------------
extern "C" void kernel_launch(void* const* d_in, const int* in_sizes, int n_in,
                              void* d_out, int out_size, void* d_ws, size_t ws_size,
                              hipStream_t stream) {
  const float* x     = (const float*)d_in[0];
  const float* lat   = (const float*)d_in[1];
  const float* shift = (const float*)d_in[2];
  const float* scale = (const float*)d_in[3];
  const float* ln1w  = (const float*)d_in[4];
  const float* ln1b  = (const float*)d_in[5];
  const float* ln2w  = (const float*)d_in[6];
  const float* ln2b  = (const float*)d_in[7];
  const float* Wq    = (const float*)d_in[8];
  const float* Wkv   = (const float*)d_in[9];
  const float* Wo    = (const float*)d_in[10];
  float* outp = (float*)d_out;

  char* ws = (char*)d_ws;
  f16* kv_in = (f16*)ws;                 ws += (size_t)MKV * DIMD * 2;          // 68 MB
  f16* Wq16  = (f16*)ws;                 ws += (size_t)1024 * 1024 * 2;         // 2 MB
  f16* Wkv16 = (f16*)ws;                 ws += (size_t)2048 * 1024 * 2;         // 4 MB
  f16* Wo16  = (f16*)ws;                 ws += (size_t)1024 * 1024 * 2;         // 2 MB
  f16* qbuf  = (f16*)ws;                 ws += (size_t)B_SZ * HEADS * N2 * DH * 2;   // 4 MB
  f16* kbuf  = (f16*)ws;                 ws += (size_t)B_SZ * HEADS * LTOT * DH * 2; // 68 MB
  f16* vbuf  = (f16*)ws;                 ws += (size_t)B_SZ * HEADS * LTOT * DH * 2; // 68 MB
  f16* aout  = (f16*)ws;                 ws += (size_t)B_SZ * N2 * DIMD * 2;         // 4 MB

  ln_mod_kernel<<<dim3(MKV), dim3(256), 0, stream>>>(x, lat, shift, scale, ln1w,
                                                     ln1b, ln2w, ln2b, kv_in);
  cast_kernel<<<dim3(1024), dim3(256), 0, stream>>>(Wq, Wq16, 1024 * 1024 / 4);
  cast_kernel<<<dim3(2048), dim3(256), 0, stream>>>(Wkv, Wkv16, 2048 * 1024 / 4);
  cast_kernel<<<dim3(1024), dim3(256), 0, stream>>>(Wo, Wo16, 1024 * 1024 / 4);

  gemm128<0><<<dim3(MKV / 128, 16), dim3(256), 0, stream>>>(kv_in, Wkv16, kbuf, vbuf);
  gemm128<1><<<dim3(16, 8), dim3(256), 0, stream>>>(kv_in, Wq16, qbuf, nullptr);
  attn_kernel<<<dim3(256), dim3(256), 0, stream>>>(qbuf, kbuf, vbuf, aout);
  gemm128<2><<<dim3(16, 8), dim3(256), 0, stream>>>(aout, Wo16, outp, nullptr);
}